// Round 8
// baseline (194.220 us; speedup 1.0000x reference)
//
#include <hip/hip_runtime.h>
#include <stdint.h>

#define Bdim 64
#define Ndim 16
#define Idim 2048
#define Ddim 32
#define Kdim 32
#define EPSV 1e-7f

#define TILE_I    2                        // i's per tile: W 8KB fp32 + x 4KB... chunks below
#define TILES_PB  16                       // tiles per block -> 32 i per block
#define NB_Y      (Idim / (TILE_I * TILES_PB))   // 64
#define CSTRIDE   1056                     // 1KB chunk + 32B pad (bank-spread)
#define NCHUNK    16                       // 8 W-chunks + 8 X-chunks per tile

typedef __attribute__((ext_vector_type(8))) short short8v;
typedef __attribute__((ext_vector_type(4))) float f32x4;

// Pure-C RNE float->bf16 pack (matches v_cvt_pk_bf16_f32 for finite inputs).
static __device__ __forceinline__ unsigned pk_rne(float a, float b) {
    unsigned ua = __float_as_uint(a);
    unsigned ub = __float_as_uint(b);
    ua = (ua + 0x7fffu + ((ua >> 16) & 1u)) >> 16;
    ub = (ub + 0x7fffu + ((ub >> 16) & 1u)) >> 16;
    return (ua & 0xffffu) | (ub << 16);
}
static __device__ __forceinline__ float bf2f(unsigned us) {
    return __uint_as_float(us << 16);
}

// global->LDS direct DMA, 16B/lane; HW dest = wave-uniform base + lane*16.
#define GLL16(g, s)                                                              \
    __builtin_amdgcn_global_load_lds(                                            \
        (const __attribute__((address_space(1))) void*)(uintptr_t)(const void*)(g), \
        (__attribute__((address_space(3))) void*)(uintptr_t)(void*)(s), 16, 0, 0)

// -------- convert_x: x[b][i][k] fp32 -> x2[i][b][k] bf16 (RNE)
__global__ __launch_bounds__(256) void convert_x(
    const float* __restrict__ x, unsigned short* __restrict__ x2)
{
    const int i  = blockIdx.x;            // 0..2047
    const int b  = threadIdx.x >> 2;      // 0..63
    const int ko = threadIdx.x & 3;       // k-octet
    const float* src = x + ((size_t)b * Idim + i) * Kdim + (ko << 3);
    float4 a = ((const float4*)src)[0];
    float4 c = ((const float4*)src)[1];
    uint4 o;
    o.x = pk_rne(a.x, a.y); o.y = pk_rne(a.z, a.w);
    o.z = pk_rne(c.x, c.y); o.w = pk_rne(c.z, c.w);
    *(uint4*)(x2 + ((size_t)i * 64 + b) * 32 + (ko << 3)) = o;
}

// -------- Pass 1 (DMA, Bc==64): u_hat[b,i,n,d] bf16 = W[n,i] @ x[b,i]; s0 += sum_i u_hat
// grid = (N, NB_Y); block = 256 (4 waves). Per tile (2 i's): 16 chunks of 1KB,
// each chunk = CONTIGUOUS global 1KB (coalesced DMA), placed at CSTRIDE=1056B in LDS
// (pad makes fragment reads 2-way-conflict-max). Compute phase: zero VMEM loads.
// vmcnt mid-loop = 8 = {prev stores(4) + next DMA(4)} -> stores never drained.
__global__ __launch_bounds__(256) void pass1_dma(
    const float* __restrict__ W, const unsigned short* __restrict__ x2,
    unsigned short* __restrict__ uhat, float* __restrict__ s0)
{
    __shared__ char lds[2][NCHUNK * CSTRIDE];   // 2 x 16.5 KB

    const int n     = blockIdx.x;
    const int iblk0 = blockIdx.y * (TILE_I * TILES_PB);
    const int tid   = threadIdx.x;
    const int l     = tid & 63;
    const int wv    = tid >> 6;                       // wave 0..3
    const int bcol  = (wv << 4) + (l & 15);           // b (MFMA N-col), 0..63
    const int krow  = l >> 4;                         // k-chunk 0..3

    const float*          Wblk = W  + ((size_t)n * Idim + iblk0) * (Ddim * Kdim);
    const unsigned short* Xblk = x2 + (size_t)iblk0 * (64 * 32);

    f32x4 acc0 = {0.f, 0.f, 0.f, 0.f};
    f32x4 acc1 = {0.f, 0.f, 0.f, 0.f};
    const f32x4 zero = {0.f, 0.f, 0.f, 0.f};

    // stage tile t into buffer buf: wave wv stages chunks {wv, 4+wv, 8+wv, 12+wv}.
    // chunk g<8: W chunk (il=g>>2, dg=g&3) = W rows d=dg*8..+8 (256 floats, contiguous)
    // chunk g>=8: X chunk (il, bg) = x2 rows b=bg*16..+16 (512 shorts, contiguous)
    auto stage = [&](int t, int buf) {
        char* base = &lds[buf][0];
        const float*          Wt = Wblk + (size_t)t * (TILE_I * 1024);
        const unsigned short* Xt = Xblk + (size_t)t * (TILE_I * 2048);
        #pragma unroll
        for (int j = 0; j < 4; ++j) {
            const int g = j * 4 + wv;                 // wave-uniform chunk id
            char* dst = base + g * CSTRIDE;
            if (g < 8) {
                const float* src = Wt + ((g >> 2) * 1024 + (g & 3) * 256) + (l << 2);
                GLL16(src, dst);
            } else {
                const int p = g - 8;
                const unsigned short* src = Xt + ((p >> 2) * 2048 + (p & 3) * 512) + (l << 3);
                GLL16(src, dst);
            }
        }
    };

    stage(0, 0);   // prologue: 4 DMA per wave in flight

    for (int t = 0; t < TILES_PB; ++t) {
        if (t + 1 < TILES_PB) stage(t + 1, (t + 1) & 1);
        // per-wave queue: [DMA_t(4), stores_{t-1}(4), DMA_{t+1}(4)]
        // mid: vmcnt(8) drains exactly DMA_t; edges: vmcnt(4).
        if (t == 0 || t == TILES_PB - 1) {
            asm volatile("s_waitcnt vmcnt(4)" ::: "memory");
        } else {
            asm volatile("s_waitcnt vmcnt(8)" ::: "memory");
        }
        __builtin_amdgcn_s_barrier();
        __builtin_amdgcn_sched_barrier(0);

        const char* base = &lds[t & 1][0];
        const int ibase = iblk0 + t * TILE_I;

        #pragma unroll
        for (int il = 0; il < TILE_I; ++il) {
            const int i = ibase + il;

            union { short8v v; unsigned u[4]; } bf, af0, af1;
            // X frag: chunk (8 + il*4 + wv), row (l&15), k-quarter (l>>4)
            bf.v = *(const short8v*)(base + (8 + il * 4 + wv) * CSTRIDE
                                          + ((l & 15) << 6) + ((l >> 4) << 4));

            // W frags: chunk (il*4 + mt*2 + ((l>>3)&1)), row (l&7), 16B at
            // (l>>4)*32 + h*16  -> banks 8*((2mt+b3+kq)%4)+4h+j : 2-way max
            const int wrow = ((l & 7) << 7) + ((l >> 4) << 5);
            const char* wc0 = base + (il * 4 + 0 + ((l >> 3) & 1)) * CSTRIDE + wrow;
            const char* wc1 = base + (il * 4 + 2 + ((l >> 3) & 1)) * CSTRIDE + wrow;
            const float4 w00 = *(const float4*)(wc0);        // mt=0, h=0
            const float4 w01 = *(const float4*)(wc0 + 16);   // mt=0, h=1
            const float4 w10 = *(const float4*)(wc1);        // mt=1, h=0
            const float4 w11 = *(const float4*)(wc1 + 16);   // mt=1, h=1
            af0.u[0] = pk_rne(w00.x, w00.y); af0.u[1] = pk_rne(w00.z, w00.w);
            af0.u[2] = pk_rne(w01.x, w01.y); af0.u[3] = pk_rne(w01.z, w01.w);
            af1.u[0] = pk_rne(w10.x, w10.y); af1.u[1] = pk_rne(w10.z, w10.w);
            af1.u[2] = pk_rne(w11.x, w11.y); af1.u[3] = pk_rne(w11.z, w11.w);

            f32x4 c0 = __builtin_amdgcn_mfma_f32_16x16x32_bf16(af0.v, bf.v, zero, 0, 0, 0);
            f32x4 c1 = __builtin_amdgcn_mfma_f32_16x16x32_bf16(af1.v, bf.v, zero, 0, 0, 0);

            // C/D: col(b)=l&15, row(d in 16-tile)=krow*4+reg
            const size_t ubase = (((size_t)bcol * Idim + i) * Ndim + n) * Ddim + (krow << 2);
            uint2 p0; p0.x = pk_rne(c0[0], c0[1]); p0.y = pk_rne(c0[2], c0[3]);
            *(uint2*)(uhat + ubase) = p0;
            uint2 p1; p1.x = pk_rne(c1[0], c1[1]); p1.y = pk_rne(c1[2], c1[3]);
            *(uint2*)(uhat + ubase + 16) = p1;

            acc0 += c0;
            acc1 += c1;
        }
        asm volatile("s_waitcnt lgkmcnt(0)" ::: "memory");  // ds_reads done before buf reuse
        __builtin_amdgcn_s_barrier();
        __builtin_amdgcn_sched_barrier(0);
    }

    float* sp = s0 + ((size_t)bcol * Ndim + n) * Ddim + (krow << 2);
    #pragma unroll
    for (int r = 0; r < 4; ++r) atomicAdd(sp + r, acc0[r]);
    #pragma unroll
    for (int r = 0; r < 4; ++r) atomicAdd(sp + 16 + r, acc1[r]);
}

// -------- Pass 1 fallback (any Bc, R4-proven body)
__global__ __launch_bounds__(256) void pass1_simple(
    const float* __restrict__ W, const float* __restrict__ x,
    unsigned short* __restrict__ uhat, float* __restrict__ s0, int bbase)
{
    const int IB = 16;
    const int n  = blockIdx.x;
    const int i0 = blockIdx.y * IB;
    const int w  = threadIdx.x >> 6;
    const int l  = threadIdx.x & 63;
    const int bcol  = (w << 4) + (l & 15);
    const int bglob = bbase + bcol;
    const int krow  = l >> 4;

    f32x4 acc0 = {0.f,0.f,0.f,0.f}, acc1 = {0.f,0.f,0.f,0.f};
    const f32x4 zero = {0.f,0.f,0.f,0.f};

    for (int ii = 0; ii < IB; ++ii) {
        const int i = i0 + ii;
        const float* xp = x + ((size_t)bglob * Idim + i) * Kdim + (krow << 3);
        float4 xa = ((const float4*)xp)[0];
        float4 xb = ((const float4*)xp)[1];
        union { short8v v; unsigned u[4]; } bf, af0, af1;
        bf.u[0]=pk_rne(xa.x,xa.y); bf.u[1]=pk_rne(xa.z,xa.w);
        bf.u[2]=pk_rne(xb.x,xb.y); bf.u[3]=pk_rne(xb.z,xb.w);

        const float* wbase = W + ((size_t)n * Idim + i) * Ddim * Kdim + (krow << 3);
        const float* wp0 = wbase + (size_t)(l & 15) * Kdim;
        float4 wa = ((const float4*)wp0)[0];
        float4 wb = ((const float4*)wp0)[1];
        af0.u[0]=pk_rne(wa.x,wa.y); af0.u[1]=pk_rne(wa.z,wa.w);
        af0.u[2]=pk_rne(wb.x,wb.y); af0.u[3]=pk_rne(wb.z,wb.w);
        const float* wp1 = wp0 + 16 * Kdim;
        float4 wc = ((const float4*)wp1)[0];
        float4 wd = ((const float4*)wp1)[1];
        af1.u[0]=pk_rne(wc.x,wc.y); af1.u[1]=pk_rne(wc.z,wc.w);
        af1.u[2]=pk_rne(wd.x,wd.y); af1.u[3]=pk_rne(wd.z,wd.w);

        f32x4 c0 = __builtin_amdgcn_mfma_f32_16x16x32_bf16(af0.v, bf.v, zero, 0,0,0);
        f32x4 c1 = __builtin_amdgcn_mfma_f32_16x16x32_bf16(af1.v, bf.v, zero, 0,0,0);

        const size_t ubase = (((size_t)bcol * Idim + i) * Ndim + n) * Ddim + (krow << 2);
        uint2 p0; p0.x=pk_rne(c0[0],c0[1]); p0.y=pk_rne(c0[2],c0[3]);
        *(uint2*)(uhat + ubase) = p0;
        uint2 p1; p1.x=pk_rne(c1[0],c1[1]); p1.y=pk_rne(c1[2],c1[3]);
        *(uint2*)(uhat + ubase + 16) = p1;
        acc0 += c0; acc1 += c1;
    }
    float* sp = s0 + ((size_t)bglob * Ndim + n) * Ddim + (krow << 2);
    #pragma unroll
    for (int r = 0; r < 4; ++r) atomicAdd(sp + r, acc0[r]);
    #pragma unroll
    for (int r = 0; r < 4; ++r) atomicAdd(sp + 16 + r, acc1[r]);
}

// -------- Routing pass: per (b,i): a[n]=u.v ; logits=(b_old)+a ; c=softmax_n ; s += c*u
template<int FIRST>
__global__ __launch_bounds__(256) void route_kernel(
    const unsigned short* __restrict__ uhat, const float* __restrict__ vin,
    float* __restrict__ bbuf, float* __restrict__ sout, int bbase)
{
    const int bc = blockIdx.x;
    const int it = blockIdx.y;
    const int w = threadIdx.x >> 6;
    const int l = threadIdx.x & 63;
    const int g = l >> 2, q = l & 3;
    const int bglob = bbase + bc;

    const float* vp = vin + ((size_t)bglob * Ndim + g) * Ddim + (q << 3);
    float vreg[8];
    *(float4*)&vreg[0] = ((const float4*)vp)[0];
    *(float4*)&vreg[4] = ((const float4*)vp)[1];

    float sacc[8];
    #pragma unroll
    for (int j = 0; j < 8; ++j) sacc[j] = 0.f;

    for (int ii = w; ii < 128; ii += 4) {
        const int i = (it << 7) + ii;
        const unsigned short* up = uhat + ((size_t)bc * Idim + i) * (Ndim * Ddim) + (l << 3);
        uint4 uraw = *(const uint4*)up;
        float u[8];
        u[0] = bf2f(uraw.x & 0xffffu); u[1] = bf2f(uraw.x >> 16);
        u[2] = bf2f(uraw.y & 0xffffu); u[3] = bf2f(uraw.y >> 16);
        u[4] = bf2f(uraw.z & 0xffffu); u[5] = bf2f(uraw.z >> 16);
        u[6] = bf2f(uraw.w & 0xffffu); u[7] = bf2f(uraw.w >> 16);

        float p = 0.f;
        #pragma unroll
        for (int j = 0; j < 8; ++j) p = fmaf(u[j], vreg[j], p);
        p += __shfl_xor(p, 1);
        p += __shfl_xor(p, 2);

        float logit = p;
        if (FIRST) {
            if (q == 0) bbuf[((size_t)bc * Idim + i) * Ndim + g] = p;
        } else {
            logit += bbuf[((size_t)bc * Idim + i) * Ndim + g];
        }
        float m = logit;
        m = fmaxf(m, __shfl_xor(m, 4));
        m = fmaxf(m, __shfl_xor(m, 8));
        m = fmaxf(m, __shfl_xor(m, 16));
        m = fmaxf(m, __shfl_xor(m, 32));
        float e = __expf(logit - m);
        float z = e;
        z += __shfl_xor(z, 4);
        z += __shfl_xor(z, 8);
        z += __shfl_xor(z, 16);
        z += __shfl_xor(z, 32);
        float c = e / z;

        #pragma unroll
        for (int j = 0; j < 8; ++j) sacc[j] = fmaf(c, u[j], sacc[j]);
    }

    __shared__ float sl[4][512];
    #pragma unroll
    for (int j = 0; j < 8; ++j) sl[w][(l << 3) + j] = sacc[j];
    __syncthreads();
    for (int e2 = threadIdx.x; e2 < 512; e2 += 256) {
        float vsum = sl[0][e2] + sl[1][e2] + sl[2][e2] + sl[3][e2];
        atomicAdd(sout + (size_t)bglob * (Ndim * Ddim) + e2, vsum);
    }
}

// -------- squash
__global__ __launch_bounds__(256) void squash_kernel(
    const float* __restrict__ s, float* __restrict__ vout, float scale, int bbase)
{
    const int tid = blockIdx.x * 256 + threadIdx.x;
    const int row = tid >> 5;
    const int d   = tid & 31;
    const size_t off = ((size_t)bbase * Ndim + row) * Ddim + d;
    float sv = s[off] * scale;
    float t = fmaf(sv, sv, EPSV);
    t += __shfl_xor(t, 1);
    t += __shfl_xor(t, 2);
    t += __shfl_xor(t, 4);
    t += __shfl_xor(t, 8);
    t += __shfl_xor(t, 16);
    float vv = sv * t / ((1.f + t) * sqrtf(t));
    vout[off] = vv;
}

extern "C" void kernel_launch(void* const* d_in, const int* in_sizes, int n_in,
                              void* d_out, int out_size, void* d_ws, size_t ws_size,
                              hipStream_t stream)
{
    (void)in_sizes; (void)n_in; (void)out_size;
    const float* x = (const float*)d_in[0];   // [B][I][K] fp32
    const float* W = (const float*)d_in[1];   // [N][I][D][K] fp32
    float* out = (float*)d_out;               // [B][N][D] fp32

    const size_t snd = (size_t)Bdim * Ndim * Ddim;
    const size_t fixed = 5 * snd * sizeof(float);

    int Bc = 64;
    while (Bc > 16) {
        size_t need = (size_t)Bc * Idim * Ndim * Ddim * 2 + (size_t)Bc * Idim * Ndim * 4 + fixed;
        if (need <= ws_size) break;
        Bc >>= 1;
    }

    char* p = (char*)d_ws;
    unsigned short* uhat = (unsigned short*)p; p += (size_t)Bc * Idim * Ndim * Ddim * 2;
    float* bbuf = (float*)p;                   p += (size_t)Bc * Idim * Ndim * 4;
    float* sbuf = (float*)p;
    float* s0 = sbuf;
    float* s1 = sbuf + snd;
    float* s2 = sbuf + 2 * snd;
    float* v0 = sbuf + 3 * snd;
    float* v1 = sbuf + 4 * snd;

    for (int bbase = 0; bbase < Bdim; bbase += Bc) {
        (void)hipMemsetAsync(sbuf, 0, 3 * snd * sizeof(float), stream);

        if (Bc == 64) {
            // x2 (8MB) aliases bbuf: x2 read only during pass1; bbuf first written in route<1>.
            unsigned short* x2 = (unsigned short*)bbuf;
            convert_x<<<dim3(Idim), 256, 0, stream>>>(x, x2);
            pass1_dma<<<dim3(Ndim, NB_Y), 256, 0, stream>>>(W, x2, uhat, s0);
        } else {
            pass1_simple<<<dim3(Ndim, Idim / 16), dim3(64 * (Bc / 16)), 0, stream>>>(
                W, x, uhat, s0, bbase);
        }
        squash_kernel<<<dim3(Bc * 2), 256, 0, stream>>>(s0, v0, 1.f / 16.f, bbase);

        route_kernel<1><<<dim3(Bc, Idim / 128), 256, 0, stream>>>(uhat, v0, bbuf, s1, bbase);
        squash_kernel<<<dim3(Bc * 2), 256, 0, stream>>>(s1, v1, 1.f, bbase);

        route_kernel<0><<<dim3(Bc, Idim / 128), 256, 0, stream>>>(uhat, v1, bbuf, s2, bbase);
        squash_kernel<<<dim3(Bc * 2), 256, 0, stream>>>(s2, out, 1.f, bbase);
    }
}

// Round 9
// 169.927 us; speedup vs baseline: 1.1430x; 1.1430x over previous
//
#include <hip/hip_runtime.h>
#include <stdint.h>

#define Bdim 64
#define Ndim 16
#define Idim 2048
#define Ddim 32
#define Kdim 32
#define EPSV 1e-7f

#define TILE_I   4                        // i's per LDS tile (W 16KB fp32, x 16KB bf16)
#define TILES_PB 16                       // tiles per block -> 64 i per block
#define NB_Y     (Idim / (TILE_I * TILES_PB))   // 32

typedef __attribute__((ext_vector_type(8))) short short8v;
typedef __attribute__((ext_vector_type(4))) float f32x4;

// Pure-C RNE float->bf16 pack (matches v_cvt_pk_bf16_f32 for finite inputs).
static __device__ __forceinline__ unsigned pk_rne(float a, float b) {
    unsigned ua = __float_as_uint(a);
    unsigned ub = __float_as_uint(b);
    ua = (ua + 0x7fffu + ((ua >> 16) & 1u)) >> 16;
    ub = (ub + 0x7fffu + ((ub >> 16) & 1u)) >> 16;
    return (ua & 0xffffu) | (ub << 16);
}
static __device__ __forceinline__ float bf2f(unsigned us) {
    return __uint_as_float(us << 16);
}

// global->LDS direct DMA, 16B per lane (dest = wave-uniform base + lane*16).
#define GLL16(g, s)                                                              \
    __builtin_amdgcn_global_load_lds(                                            \
        (const __attribute__((address_space(1))) void*)(uintptr_t)(const void*)(g), \
        (__attribute__((address_space(3))) void*)(uintptr_t)(void*)(s), 16, 0, 0)

// -------- convert_x: x[b][i][k] fp32 -> x2[i][b][k] bf16 (RNE), fragment-friendly order
__global__ __launch_bounds__(256) void convert_x(
    const float* __restrict__ x, unsigned short* __restrict__ x2)
{
    const int i  = blockIdx.x;            // 0..2047
    const int b  = threadIdx.x >> 2;      // 0..63
    const int ko = threadIdx.x & 3;       // k-octet
    const float* src = x + ((size_t)b * Idim + i) * Kdim + (ko << 3);
    float4 a = ((const float4*)src)[0];
    float4 c = ((const float4*)src)[1];
    uint4 o;
    o.x = pk_rne(a.x, a.y); o.y = pk_rne(a.z, a.w);
    o.z = pk_rne(c.x, c.y); o.w = pk_rne(c.z, c.w);
    *(uint4*)(x2 + ((size_t)i * 64 + b) * 32 + (ko << 3)) = o;
}

// -------- Pass 1 (DMA, Bc==64): u_hat[i,n,b,d] (bf16) = W[n,i] @ x[b,i]; s0 += sum_i u_hat
// grid = (N, NB_Y); block = 256 (4 waves). Per tile: W 16KB (fragment-permuted src ->
// linear LDS) + x2 16KB (linear copy), double-buffered. Compute phase has NO VMEM loads.
// u_hat layout [i][n][b][d]: each wave's two uint2 stores cover ONE contiguous 1KB run
// (block: 4KB contiguous per (i,n)) -> merged write bursts, fast store-acks (the R7->R9
// single-variable change; scattered 2MB-stride stores are the suspected ack serializer).
__global__ __launch_bounds__(256) void pass1_dma(
    const float* __restrict__ W, const unsigned short* __restrict__ x2,
    unsigned short* __restrict__ uhat, float* __restrict__ s0)
{
    __shared__ float          ldsW[2][TILE_I * 1024];   // 2 x 16 KB
    __shared__ unsigned short ldsX[2][TILE_I * 2048];   // 2 x 16 KB

    const int n     = blockIdx.x;
    const int iblk0 = blockIdx.y * (TILE_I * TILES_PB);
    const int tid   = threadIdx.x;
    const int l     = tid & 63;
    const int bcol  = ((tid >> 6) << 4) + (l & 15);     // b (MFMA N-col), 0..63
    const int krow  = l >> 4;                           // k-chunk 0..3

    const float*          Wblk = W  + ((size_t)n * Idim + iblk0) * (Ddim * Kdim);
    const unsigned short* Xblk = x2 + (size_t)iblk0 * (64 * 32);

    f32x4 acc0 = {0.f, 0.f, 0.f, 0.f};
    f32x4 acc1 = {0.f, 0.f, 0.f, 0.f};
    const f32x4 zero = {0.f, 0.f, 0.f, 0.f};

    // ---- staging (4 W-chunks + 4 x-chunks per thread = 8 DMA instrs per wave per tile)
    auto stage = [&](int t, int buf) {
        const float* Wt = Wblk + (size_t)t * (TILE_I * 1024);
        float* dw = &ldsW[buf][0];
        #pragma unroll
        for (int j = 0; j < 4; ++j) {
            const int c  = j * 256 + tid;               // chunk 0..1023
            const int lc = c & 63, h = (c >> 6) & 1, mt = (c >> 7) & 1, il = c >> 8;
            const float* src = Wt + il * 1024 + ((mt << 4) + (lc & 15)) * 32
                                  + ((lc >> 4) << 3) + (h << 2);
            GLL16(src, dw + (size_t)c * 4);
        }
        const unsigned short* Xt = Xblk + (size_t)t * (TILE_I * 2048);
        unsigned short* dx = &ldsX[buf][0];
        #pragma unroll
        for (int j = 0; j < 4; ++j) {
            const int c = j * 256 + tid;                // linear 16B chunks
            GLL16(Xt + (size_t)c * 8, dx + (size_t)c * 8);
        }
    };

    stage(0, 0);   // prologue

    for (int t = 0; t < TILES_PB; ++t) {
        if (t + 1 < TILES_PB) stage(t + 1, (t + 1) & 1);
        // in-order vmcnt: drains tile t's DMAs (and older stores); leaves tile t+1's
        // 8 DMAs in flight across both barriers.
        asm volatile("s_waitcnt vmcnt(8)" ::: "memory");
        __builtin_amdgcn_s_barrier();
        __builtin_amdgcn_sched_barrier(0);

        const float*          lw = &ldsW[t & 1][0];
        const unsigned short* lx = &ldsX[t & 1][0];
        const int ibase = iblk0 + t * TILE_I;

        #pragma unroll
        for (int il = 0; il < TILE_I; ++il) {
            const int i = ibase + il;

            union { short8v v; unsigned u[4]; } bf, af0, af1;
            // x frag: bf16x8 straight from LDS (already converted)
            bf.v = *(const short8v*)(lx + il * 2048 + bcol * 32 + (krow << 3));

            // W frags: lane-consecutive chunks (il, mt, h, l) -> conflict-free b128
            const float4 w00 = *(const float4*)(lw + ((il * 256 + l)       << 2));
            const float4 w01 = *(const float4*)(lw + ((il * 256 + 64 + l)  << 2));
            const float4 w10 = *(const float4*)(lw + ((il * 256 + 128 + l) << 2));
            const float4 w11 = *(const float4*)(lw + ((il * 256 + 192 + l) << 2));
            af0.u[0] = pk_rne(w00.x, w00.y); af0.u[1] = pk_rne(w00.z, w00.w);
            af0.u[2] = pk_rne(w01.x, w01.y); af0.u[3] = pk_rne(w01.z, w01.w);
            af1.u[0] = pk_rne(w10.x, w10.y); af1.u[1] = pk_rne(w10.z, w10.w);
            af1.u[2] = pk_rne(w11.x, w11.y); af1.u[3] = pk_rne(w11.z, w11.w);

            f32x4 c0 = __builtin_amdgcn_mfma_f32_16x16x32_bf16(af0.v, bf.v, zero, 0, 0, 0);
            f32x4 c1 = __builtin_amdgcn_mfma_f32_16x16x32_bf16(af1.v, bf.v, zero, 0, 0, 0);

            // C/D layout: col(b)=l&15, row(d in 16-tile)=krow*4+reg
            // u_hat[i][n][b][d]: wave-contiguous 1KB across (bcol,krow,p0/p1)
            const size_t ubase = (((size_t)i * Ndim + n) * 64 + bcol) * Ddim + (krow << 2);
            uint2 p0; p0.x = pk_rne(c0[0], c0[1]); p0.y = pk_rne(c0[2], c0[3]);
            *(uint2*)(uhat + ubase) = p0;
            uint2 p1; p1.x = pk_rne(c1[0], c1[1]); p1.y = pk_rne(c1[2], c1[3]);
            *(uint2*)(uhat + ubase + 16) = p1;

            acc0 += c0;
            acc1 += c1;
        }
        asm volatile("s_waitcnt lgkmcnt(0)" ::: "memory");  // all ds_reads done before buf reuse
        __builtin_amdgcn_s_barrier();
        __builtin_amdgcn_sched_barrier(0);
    }

    float* sp = s0 + ((size_t)bcol * Ndim + n) * Ddim + (krow << 2);
    #pragma unroll
    for (int r = 0; r < 4; ++r) atomicAdd(sp + r, acc0[r]);
    #pragma unroll
    for (int r = 0; r < 4; ++r) atomicAdd(sp + 16 + r, acc1[r]);
}

// -------- Pass 1 fallback (any Bc, R4-proven body; u_hat layout [i][n][b_local][d])
__global__ __launch_bounds__(256) void pass1_simple(
    const float* __restrict__ W, const float* __restrict__ x,
    unsigned short* __restrict__ uhat, float* __restrict__ s0, int bbase, int Bc)
{
    const int IB = 16;
    const int n  = blockIdx.x;
    const int i0 = blockIdx.y * IB;
    const int w  = threadIdx.x >> 6;
    const int l  = threadIdx.x & 63;
    const int bcol  = (w << 4) + (l & 15);
    const int bglob = bbase + bcol;
    const int krow  = l >> 4;

    f32x4 acc0 = {0.f,0.f,0.f,0.f}, acc1 = {0.f,0.f,0.f,0.f};
    const f32x4 zero = {0.f,0.f,0.f,0.f};

    for (int ii = 0; ii < IB; ++ii) {
        const int i = i0 + ii;
        const float* xp = x + ((size_t)bglob * Idim + i) * Kdim + (krow << 3);
        float4 xa = ((const float4*)xp)[0];
        float4 xb = ((const float4*)xp)[1];
        union { short8v v; unsigned u[4]; } bf, af0, af1;
        bf.u[0]=pk_rne(xa.x,xa.y); bf.u[1]=pk_rne(xa.z,xa.w);
        bf.u[2]=pk_rne(xb.x,xb.y); bf.u[3]=pk_rne(xb.z,xb.w);

        const float* wbase = W + ((size_t)n * Idim + i) * Ddim * Kdim + (krow << 3);
        const float* wp0 = wbase + (size_t)(l & 15) * Kdim;
        float4 wa = ((const float4*)wp0)[0];
        float4 wb = ((const float4*)wp0)[1];
        af0.u[0]=pk_rne(wa.x,wa.y); af0.u[1]=pk_rne(wa.z,wa.w);
        af0.u[2]=pk_rne(wb.x,wb.y); af0.u[3]=pk_rne(wb.z,wb.w);
        const float* wp1 = wp0 + 16 * Kdim;
        float4 wc = ((const float4*)wp1)[0];
        float4 wd = ((const float4*)wp1)[1];
        af1.u[0]=pk_rne(wc.x,wc.y); af1.u[1]=pk_rne(wc.z,wc.w);
        af1.u[2]=pk_rne(wd.x,wd.y); af1.u[3]=pk_rne(wd.z,wd.w);

        f32x4 c0 = __builtin_amdgcn_mfma_f32_16x16x32_bf16(af0.v, bf.v, zero, 0,0,0);
        f32x4 c1 = __builtin_amdgcn_mfma_f32_16x16x32_bf16(af1.v, bf.v, zero, 0,0,0);

        const size_t ubase = (((size_t)i * Ndim + n) * Bc + bcol) * Ddim + (krow << 2);
        uint2 p0; p0.x=pk_rne(c0[0],c0[1]); p0.y=pk_rne(c0[2],c0[3]);
        *(uint2*)(uhat + ubase) = p0;
        uint2 p1; p1.x=pk_rne(c1[0],c1[1]); p1.y=pk_rne(c1[2],c1[3]);
        *(uint2*)(uhat + ubase + 16) = p1;
        acc0 += c0; acc1 += c1;
    }
    float* sp = s0 + ((size_t)bglob * Ndim + n) * Ddim + (krow << 2);
    #pragma unroll
    for (int r = 0; r < 4; ++r) atomicAdd(sp + r, acc0[r]);
    #pragma unroll
    for (int r = 0; r < 4; ++r) atomicAdd(sp + 16 + r, acc1[r]);
}

// -------- Routing pass: per (b,i): a[n]=u.v ; logits=(b_old)+a ; c=softmax_n ; s += c*u
// u_hat layout [i][n][b][d]: lane (g,q) reads 16B at ((i*16+g)*Bc+bc)*32 + q*8
template<int FIRST>
__global__ __launch_bounds__(256) void route_kernel(
    const unsigned short* __restrict__ uhat, const float* __restrict__ vin,
    float* __restrict__ bbuf, float* __restrict__ sout, int bbase, int Bc)
{
    const int bc = blockIdx.x;
    const int it = blockIdx.y;
    const int w = threadIdx.x >> 6;
    const int l = threadIdx.x & 63;
    const int g = l >> 2, q = l & 3;
    const int bglob = bbase + bc;

    const float* vp = vin + ((size_t)bglob * Ndim + g) * Ddim + (q << 3);
    float vreg[8];
    *(float4*)&vreg[0] = ((const float4*)vp)[0];
    *(float4*)&vreg[4] = ((const float4*)vp)[1];

    float sacc[8];
    #pragma unroll
    for (int j = 0; j < 8; ++j) sacc[j] = 0.f;

    for (int ii = w; ii < 128; ii += 4) {
        const int i = (it << 7) + ii;
        const unsigned short* up = uhat + (((size_t)i * Ndim + g) * Bc + bc) * Ddim + (q << 3);
        uint4 uraw = *(const uint4*)up;
        float u[8];
        u[0] = bf2f(uraw.x & 0xffffu); u[1] = bf2f(uraw.x >> 16);
        u[2] = bf2f(uraw.y & 0xffffu); u[3] = bf2f(uraw.y >> 16);
        u[4] = bf2f(uraw.z & 0xffffu); u[5] = bf2f(uraw.z >> 16);
        u[6] = bf2f(uraw.w & 0xffffu); u[7] = bf2f(uraw.w >> 16);

        float p = 0.f;
        #pragma unroll
        for (int j = 0; j < 8; ++j) p = fmaf(u[j], vreg[j], p);
        p += __shfl_xor(p, 1);
        p += __shfl_xor(p, 2);

        float logit = p;
        if (FIRST) {
            if (q == 0) bbuf[((size_t)bc * Idim + i) * Ndim + g] = p;
        } else {
            logit += bbuf[((size_t)bc * Idim + i) * Ndim + g];
        }
        float m = logit;
        m = fmaxf(m, __shfl_xor(m, 4));
        m = fmaxf(m, __shfl_xor(m, 8));
        m = fmaxf(m, __shfl_xor(m, 16));
        m = fmaxf(m, __shfl_xor(m, 32));
        float e = __expf(logit - m);
        float z = e;
        z += __shfl_xor(z, 4);
        z += __shfl_xor(z, 8);
        z += __shfl_xor(z, 16);
        z += __shfl_xor(z, 32);
        float c = e / z;

        #pragma unroll
        for (int j = 0; j < 8; ++j) sacc[j] = fmaf(c, u[j], sacc[j]);
    }

    __shared__ float sl[4][512];
    #pragma unroll
    for (int j = 0; j < 8; ++j) sl[w][(l << 3) + j] = sacc[j];
    __syncthreads();
    for (int e2 = threadIdx.x; e2 < 512; e2 += 256) {
        float vsum = sl[0][e2] + sl[1][e2] + sl[2][e2] + sl[3][e2];
        atomicAdd(sout + (size_t)bglob * (Ndim * Ddim) + e2, vsum);
    }
}

// -------- squash
__global__ __launch_bounds__(256) void squash_kernel(
    const float* __restrict__ s, float* __restrict__ vout, float scale, int bbase)
{
    const int tid = blockIdx.x * 256 + threadIdx.x;
    const int row = tid >> 5;
    const int d   = tid & 31;
    const size_t off = ((size_t)bbase * Ndim + row) * Ddim + d;
    float sv = s[off] * scale;
    float t = fmaf(sv, sv, EPSV);
    t += __shfl_xor(t, 1);
    t += __shfl_xor(t, 2);
    t += __shfl_xor(t, 4);
    t += __shfl_xor(t, 8);
    t += __shfl_xor(t, 16);
    float vv = sv * t / ((1.f + t) * sqrtf(t));
    vout[off] = vv;
}

extern "C" void kernel_launch(void* const* d_in, const int* in_sizes, int n_in,
                              void* d_out, int out_size, void* d_ws, size_t ws_size,
                              hipStream_t stream)
{
    (void)in_sizes; (void)n_in; (void)out_size;
    const float* x = (const float*)d_in[0];   // [B][I][K] fp32
    const float* W = (const float*)d_in[1];   // [N][I][D][K] fp32
    float* out = (float*)d_out;               // [B][N][D] fp32

    const size_t snd = (size_t)Bdim * Ndim * Ddim;
    const size_t fixed = 5 * snd * sizeof(float);

    int Bc = 64;
    while (Bc > 16) {
        size_t need = (size_t)Bc * Idim * Ndim * Ddim * 2 + (size_t)Bc * Idim * Ndim * 4 + fixed;
        if (need <= ws_size) break;
        Bc >>= 1;
    }

    char* p = (char*)d_ws;
    unsigned short* uhat = (unsigned short*)p; p += (size_t)Bc * Idim * Ndim * Ddim * 2;
    float* bbuf = (float*)p;                   p += (size_t)Bc * Idim * Ndim * 4;
    float* sbuf = (float*)p;
    float* s0 = sbuf;
    float* s1 = sbuf + snd;
    float* s2 = sbuf + 2 * snd;
    float* v0 = sbuf + 3 * snd;
    float* v1 = sbuf + 4 * snd;

    for (int bbase = 0; bbase < Bdim; bbase += Bc) {
        (void)hipMemsetAsync(sbuf, 0, 3 * snd * sizeof(float), stream);

        if (Bc == 64) {
            // x2 (8MB) aliases bbuf: x2 read only during pass1; bbuf first written in route<1>.
            unsigned short* x2 = (unsigned short*)bbuf;
            convert_x<<<dim3(Idim), 256, 0, stream>>>(x, x2);
            pass1_dma<<<dim3(Ndim, NB_Y), 256, 0, stream>>>(W, x2, uhat, s0);
        } else {
            pass1_simple<<<dim3(Ndim, Idim / 16), dim3(64 * (Bc / 16)), 0, stream>>>(
                W, x, uhat, s0, bbase, Bc);
        }
        squash_kernel<<<dim3(Bc * 2), 256, 0, stream>>>(s0, v0, 1.f / 16.f, bbase);

        route_kernel<1><<<dim3(Bc, Idim / 128), 256, 0, stream>>>(uhat, v0, bbuf, s1, bbase, Bc);
        squash_kernel<<<dim3(Bc * 2), 256, 0, stream>>>(s1, v1, 1.f, bbase);

        route_kernel<0><<<dim3(Bc, Idim / 128), 256, 0, stream>>>(uhat, v1, bbuf, s2, bbase, Bc);
        squash_kernel<<<dim3(Bc * 2), 256, 0, stream>>>(s2, out, 1.f, bbase);
    }
}